// Round 1
// 1306.106 us; speedup vs baseline: 1.2385x; 1.2385x over previous
//
#include <hip/hip_runtime.h>
#include <hip/hip_bf16.h>

#define N_TOK 16384
#define C_DIM 1024
#define H_DIM 4096
#define E_NUM 8
#define NK_TOT 32768

typedef unsigned short u16;
typedef unsigned int u32;
typedef float f4 __attribute__((ext_vector_type(4)));
typedef __bf16 bf8 __attribute__((ext_vector_type(8)));

union V16 { f4 f; bf8 b; };

__device__ __forceinline__ u16 f2bf(float x) {
  // round-to-nearest-even fp32 -> bf16
  u32 u = __builtin_bit_cast(u32, x);
  u = (u + 0x7fffu + ((u >> 16) & 1u)) >> 16;
  return (u16)u;
}

// ---------------- x fp32 -> bf16 ----------------
__global__ __launch_bounds__(256) void cvt_x_k(const float* __restrict__ src, u16* __restrict__ dst) {
  const size_t g = (size_t)blockIdx.x * 256 + threadIdx.x;   // over N*C/4
  const f4 v = ((const f4*)src)[g];
  u32 lo = (u32)f2bf(v[0]) | ((u32)f2bf(v[1]) << 16);
  u32 hi = (u32)f2bf(v[2]) | ((u32)f2bf(v[3]) << 16);
  ((uint2*)dst)[g] = make_uint2(lo, hi);
}

// ------------- weight transpose + cvt: src fp32 [R][S] -> dst bf16 [S][R], per expert (grid.z) -------------
__global__ __launch_bounds__(256) void transpose_cvt_k(const float* __restrict__ src, u16* __restrict__ dst,
                                                       int R, int S) {
  __shared__ float tile[64][65];
  const size_t eoff = (size_t)blockIdx.z * R * S;
  const int s0 = blockIdx.x * 64, r0 = blockIdx.y * 64;
  for (int p = threadIdx.x; p < 4096; p += 256) {
    int r = p >> 6, s = p & 63;
    tile[r][s] = src[eoff + (size_t)(r0 + r) * S + (s0 + s)];
  }
  __syncthreads();
  for (int p = threadIdx.x; p < 4096; p += 256) {
    int sN = p >> 6, rN = p & 63;
    dst[eoff + (size_t)(s0 + sN) * R + (r0 + rN)] = f2bf(tile[rN][sN]);
  }
}

// ---------------- router: one wave per token ----------------
__global__ __launch_bounds__(256) void router_k(const float* __restrict__ x, const float* __restrict__ rw,
                                                const float* __restrict__ rb, int* __restrict__ idx,
                                                float* __restrict__ vals, u32* __restrict__ cnt,
                                                float* __restrict__ imp) {
  __shared__ float s_imp[E_NUM];
  __shared__ u32 s_cnt[E_NUM];
  if (threadIdx.x < E_NUM) { s_imp[threadIdx.x] = 0.f; s_cnt[threadIdx.x] = 0u; }
  __syncthreads();
  const int wave = threadIdx.x >> 6, lane = threadIdx.x & 63;
  const int t = blockIdx.x * 4 + wave;
  const float* xr = x + (size_t)t * C_DIM;
  float a[E_NUM] = {0.f, 0.f, 0.f, 0.f, 0.f, 0.f, 0.f, 0.f};
  for (int c = lane; c < C_DIM; c += 64) {
    float xv = xr[c];
    const float* w = rw + c * E_NUM;
#pragma unroll
    for (int e = 0; e < E_NUM; ++e) a[e] = fmaf(xv, w[e], a[e]);
  }
#pragma unroll
  for (int e = 0; e < E_NUM; ++e) {
#pragma unroll
    for (int off = 32; off > 0; off >>= 1) a[e] += __shfl_xor(a[e], off, 64);
  }
  if (lane == 0) {
    float p[E_NUM]; float m = -1e30f, s = 0.f;
#pragma unroll
    for (int e = 0; e < E_NUM; ++e) { p[e] = a[e] + rb[e]; m = fmaxf(m, p[e]); }
#pragma unroll
    for (int e = 0; e < E_NUM; ++e) { p[e] = expf(p[e] - m); s += p[e]; }
    const float inv = 1.f / s;
#pragma unroll
    for (int e = 0; e < E_NUM; ++e) p[e] *= inv;
    int e0 = 0; float v0 = p[0];
#pragma unroll
    for (int e = 1; e < E_NUM; ++e) if (p[e] > v0) { v0 = p[e]; e0 = e; }
    int e1 = -1; float v1 = -1e30f;
#pragma unroll
    for (int e = 0; e < E_NUM; ++e) if (e != e0 && p[e] > v1) { v1 = p[e]; e1 = e; }
    idx[2 * t] = e0; idx[2 * t + 1] = e1;
    vals[2 * t] = v0; vals[2 * t + 1] = v1;
    atomicAdd(&s_cnt[e0], 1u); atomicAdd(&s_cnt[e1], 1u);
#pragma unroll
    for (int e = 0; e < E_NUM; ++e) atomicAdd(&s_imp[e], p[e]);
  }
  __syncthreads();
  if (threadIdx.x < E_NUM) {
    atomicAdd(&cnt[threadIdx.x], s_cnt[threadIdx.x]);
    atomicAdd(&imp[threadIdx.x], s_imp[threadIdx.x]);
  }
}

__global__ void offsets_k(const u32* __restrict__ cnt, int* __restrict__ off) {
  if (threadIdx.x == 0) {
    int s = 0;
    for (int e = 0; e < E_NUM; ++e) { off[e] = s; s += (int)cnt[e]; }
    off[E_NUM] = s;
  }
}

// ---------------- scatter tokens into per-expert lists (stride N_TOK) ----------------
__global__ __launch_bounds__(256) void scatter_k(const int* __restrict__ idx, u32* __restrict__ cursor,
                                                 int* __restrict__ tl) {
  __shared__ u32 lcnt[E_NUM];
  __shared__ u32 base[E_NUM];
  if (threadIdx.x < E_NUM) lcnt[threadIdx.x] = 0u;
  __syncthreads();
  const int t = blockIdx.x * 256 + threadIdx.x;
  const int e0 = idx[2 * t], e1 = idx[2 * t + 1];
  const u32 p0 = atomicAdd(&lcnt[e0], 1u);
  const u32 p1 = atomicAdd(&lcnt[e1], 1u);
  __syncthreads();
  if (threadIdx.x < E_NUM) base[threadIdx.x] = atomicAdd(&cursor[threadIdx.x], lcnt[threadIdx.x]);
  __syncthreads();
  tl[e0 * N_TOK + (int)(base[e0] + p0)] = t;
  tl[e1 * N_TOK + (int)(base[e1] + p1)] = t;
}

// ---------------- grouped GEMM: 128x128 tile, BK=64, 4 waves, mfma 16x16x32 bf16 ----------------
// Staging: global_load_lds dwordx4 (16B/lane), linear LDS dest, XOR-swizzled SOURCE slot
// (slot ^= row&7) so that swizzled ds_read_b128 fragment reads are bank-conflict-free.
// MODE 0: h = relu(gather(x_bf) @ w1t^T + b1)  -> h_out (bf16)
// MODE 1: out_acc[token] += h @ w2t^T          (fp32 atomicAdd into d_out)
template <int MODE>
__global__ __launch_bounds__(256, 2) void moe_gemm(
    const u16* __restrict__ A_base, const u16* __restrict__ Bt, const float* __restrict__ bias,
    u16* __restrict__ h_out, float* out_acc, const int* __restrict__ token_list,
    const u32* __restrict__ counts, const int* __restrict__ offsets,
    int K_len, int B_stride, int B_ncap, int n_base, int k_off, int A_stride, int h_stride) {
  const int e = blockIdx.z;
  const int n_e = (int)counts[e];
  const int m0 = blockIdx.x * 128;
  if (m0 >= n_e) return;
  const int off_e = offsets[e];
  const int nb = blockIdx.y * 128;

  // LDS layout: [row(128)][k(64)] bf16, 128 B per row, 16 KB per matrix
  __shared__ u16 lA[128 * 64];
  __shared__ u16 lB[128 * 64];

  const int tid = threadIdx.x;
  const int lane = tid & 63;
  const int wave = tid >> 6;

  // Staging geometry: per K-step the 16 KB tile is filled in 4 rounds of
  // 256 threads x 16 B. Thread (wave,lane), round q writes LDS bytes
  // [q*4096 + wave*1024 + lane*16), i.e. row = q*32 + wave*8 + (lane>>3),
  // 16B-slot = lane&7. Source slot is XOR-swizzled by row&7 (== lane>>3).
  const int sub = lane >> 3;            // == row & 7 for every round
  const int c16 = lane & 7;             // LDS 16B-slot within row
  const int gslot = c16 ^ sub;          // swizzled global 16B-slot
  const u16* a_src[4];
  const u16* b_src[4];
#pragma unroll
  for (int q = 0; q < 4; ++q) {
    const int r = q * 32 + wave * 8 + sub;            // tile row 0..127
    int ar = m0 + r; if (ar > n_e - 1) ar = n_e - 1;  // clamp tail rows
    size_t arow;
    if (MODE == 0) arow = (size_t)token_list[e * N_TOK + ar] * A_stride;
    else           arow = (size_t)(off_e + ar) * A_stride;
    a_src[q] = A_base + arow + gslot * 8;
    b_src[q] = Bt + ((size_t)e * B_ncap + (n_base + nb + r)) * B_stride + k_off + gslot * 8;
  }

  f4 acc[4][4];
#pragma unroll
  for (int i = 0; i < 4; ++i)
#pragma unroll
    for (int j = 0; j < 4; ++j) acc[i][j] = (f4){0.f, 0.f, 0.f, 0.f};

  const int quad = lane >> 4, l16 = lane & 15;
  const int wm = (wave >> 1) * 64;
  const int wn = (wave & 1) * 64;
  const int p7 = l16 & 7;               // == fragment row & 7 (wm, i*16 are 0 mod 8)

  const int iters = K_len >> 6;
  for (int it = 0; it < iters; ++it) {
    // ---- stage current K-tile: 8 global_load_lds dwordx4 per thread ----
#pragma unroll
    for (int q = 0; q < 4; ++q) {
      __builtin_amdgcn_global_load_lds(
          (const __attribute__((address_space(1))) void*)a_src[q],
          (__attribute__((address_space(3))) void*)(&lA[q * 2048 + wave * 512]),
          16, 0, 0);
      __builtin_amdgcn_global_load_lds(
          (const __attribute__((address_space(1))) void*)b_src[q],
          (__attribute__((address_space(3))) void*)(&lB[q * 2048 + wave * 512]),
          16, 0, 0);
      a_src[q] += 64; b_src[q] += 64;
    }
    __syncthreads();   // drains vmcnt(0): tile resident

    // ---- compute: 2 k-substeps x 16 MFMA ----
#pragma unroll
    for (int kk = 0; kk < 2; ++kk) {
      const int sl = (((kk << 2) | quad) ^ p7) * 8;   // swizzled ds_read slot (u16 units)
      V16 af[4], bfr[4];
#pragma unroll
      for (int i = 0; i < 4; ++i) {
        af[i].f  = *(const f4*)&lA[(wm + i * 16 + l16) * 64 + sl];
        bfr[i].f = *(const f4*)&lB[(wn + i * 16 + l16) * 64 + sl];
      }
#pragma unroll
      for (int i = 0; i < 4; ++i)
#pragma unroll
        for (int j = 0; j < 4; ++j)
          acc[i][j] = __builtin_amdgcn_mfma_f32_16x16x32_bf16(af[i].b, bfr[j].b, acc[i][j], 0, 0, 0);
    }
    __syncthreads();   // all waves done reading before next overwrite
  }

  // epilogue; C/D layout: col = lane&15, row = quad*4 + reg
#pragma unroll
  for (int i = 0; i < 4; ++i) {
    const int lm = wm + i * 16 + quad * 4;
#pragma unroll
    for (int j = 0; j < 4; ++j) {
      const int ncol = nb + wn + j * 16 + l16;
#pragma unroll
      for (int r = 0; r < 4; ++r) {
        const int row = m0 + lm + r;
        if (row < n_e) {
          float v = acc[i][j][r];
          if (MODE == 0) {
            v += bias[e * H_DIM + n_base + ncol];
            v = fmaxf(v, 0.f);
            h_out[(size_t)(off_e + row) * h_stride + ncol] = f2bf(v);
          } else {
            const int tok = token_list[e * N_TOK + row];
            atomicAdd(&out_acc[(size_t)tok * C_DIM + ncol], v);
          }
        }
      }
    }
  }
}

// ---------------- final (in place on fp32 d_out): out = w*(acc + b2[e0] + b2[e1]); aux ----------------
__global__ __launch_bounds__(256) void final_k(float* out, const float* __restrict__ vals,
                                               const int* __restrict__ idx, const float* __restrict__ b2,
                                               const u32* __restrict__ cnt, const float* __restrict__ imp) {
  const size_t g = (size_t)blockIdx.x * 256 + threadIdx.x;  // over N*C/4
  const int t = (int)(g >> 8);
  const int c4 = (int)(g & 255);
  const float w = vals[t];  // faithful quirk: w_tok[t] = topk_vals.flat[t]
  const int e0 = idx[2 * t], e1 = idx[2 * t + 1];
  f4 a = ((const f4*)out)[g];
  f4 u = ((const f4*)(b2 + (size_t)e0 * C_DIM))[c4];
  f4 v = ((const f4*)(b2 + (size_t)e1 * C_DIM))[c4];
  f4 r;
#pragma unroll
  for (int q = 0; q < 4; ++q) r[q] = w * (a[q] + u[q] + v[q]);
  ((f4*)out)[g] = r;
  if (g == 0) {
    float aux = 0.f;
    for (int e = 0; e < E_NUM; ++e)
      aux += (imp[e] / (float)N_TOK) * ((float)cnt[e] / (float)(N_TOK * 2));
    out[(size_t)N_TOK * C_DIM] = aux;
  }
}

extern "C" void kernel_launch(void* const* d_in, const int* in_sizes, int n_in,
                              void* d_out, int out_size, void* d_ws, size_t ws_size,
                              hipStream_t stream) {
  const float* x  = (const float*)d_in[0];
  const float* rw = (const float*)d_in[1];
  const float* rb = (const float*)d_in[2];
  const float* w1 = (const float*)d_in[3];
  const float* b1 = (const float*)d_in[4];
  const float* w2 = (const float*)d_in[5];
  const float* b2 = (const float*)d_in[6];
  float* out = (float*)d_out;   // fp32 output (reference returns float32)

  char* ws = (char*)d_ws;
  size_t off = 0;
  auto alloc = [&](size_t bytes) -> void* {
    void* p = ws + off; off += (bytes + 255) & ~(size_t)255; return p;
  };
  u16* x_bf    = (u16*)alloc((size_t)N_TOK * C_DIM * 2);
  u16* w1t     = (u16*)alloc((size_t)E_NUM * H_DIM * C_DIM * 2);
  u16* w2t     = (u16*)alloc((size_t)E_NUM * C_DIM * H_DIM * 2);
  int* tl      = (int*)alloc((size_t)E_NUM * N_TOK * 4);
  int* idx     = (int*)alloc((size_t)N_TOK * 2 * 4);
  float* vals  = (float*)alloc((size_t)N_TOK * 2 * 4);
  u32* small   = (u32*)alloc(256);
  u32* cnt     = small;                 // [8]
  u32* cursor  = small + 8;             // [8]
  float* imp   = (float*)(small + 16);  // [8]
  int* offs    = (int*)(small + 24);    // [9]

  // h buffer: chunk H if workspace is tight
  size_t rem = (ws_size > off) ? ws_size - off : 0;
  int NC = 1;
  while (NC < 32 && (size_t)NK_TOT * (H_DIM / NC) * 2 > rem) NC <<= 1;
  const int Hc = H_DIM / NC;
  u16* h_buf = (u16*)(ws + off);

  // zero the fp32 accumulator (= d_out; timed replays poison it to 0xAA)
  hipMemsetAsync(out, 0, (size_t)out_size * sizeof(float), stream);
  hipMemsetAsync(small, 0, 256, stream);

  cvt_x_k<<<(N_TOK * C_DIM / 4) / 256, 256, 0, stream>>>(x, x_bf);
  transpose_cvt_k<<<dim3(H_DIM / 64, C_DIM / 64, E_NUM), 256, 0, stream>>>(w1, w1t, C_DIM, H_DIM);
  transpose_cvt_k<<<dim3(C_DIM / 64, H_DIM / 64, E_NUM), 256, 0, stream>>>(w2, w2t, H_DIM, C_DIM);
  router_k<<<N_TOK / 4, 256, 0, stream>>>(x, rw, rb, idx, vals, cnt, imp);
  offsets_k<<<1, 64, 0, stream>>>(cnt, offs);
  scatter_k<<<N_TOK / 256, 256, 0, stream>>>(idx, cursor, tl);

  for (int ci = 0; ci < NC; ++ci) {
    moe_gemm<0><<<dim3(128, Hc / 128, E_NUM), 256, 0, stream>>>(
        x_bf, w1t, b1, h_buf, nullptr, tl, cnt, offs,
        /*K_len*/ C_DIM, /*B_stride*/ C_DIM, /*B_ncap*/ H_DIM,
        /*n_base*/ ci * Hc, /*k_off*/ 0, /*A_stride*/ C_DIM, /*h_stride*/ Hc);
    moe_gemm<1><<<dim3(128, C_DIM / 128, E_NUM), 256, 0, stream>>>(
        h_buf, w2t, nullptr, nullptr, out, tl, cnt, offs,
        /*K_len*/ Hc, /*B_stride*/ H_DIM, /*B_ncap*/ C_DIM,
        /*n_base*/ 0, /*k_off*/ ci * Hc, /*A_stride*/ Hc, /*h_stride*/ 0);
  }

  final_k<<<(N_TOK * C_DIM / 4) / 256, 256, 0, stream>>>(out, vals, idx, b2, cnt, imp);
}